// Round 1
// baseline (3179.841 us; speedup 1.0000x reference)
//
#include <hip/hip_runtime.h>
#include <hip/hip_bf16.h>
#include <math.h>

// ---------------------------------------------------------------------------
// GCAModel forward, decomposed (all f32 this round):
//   B=16 CDD=5 HIS=50 S=20 T=41 E=300 F=256 H=16 DV=16 QD=200
//   fusion = [cdd(0..19) | SEP@20 | his(21..40)]
// Sharing exploited:
//   XC [80][20][256]  : conv out t=0..19 (cdd-only, per (b,c))
//   XH [800][20][256] : conv out t=21..40 (his-only, per (b,h))
//   XM [4000][256]    : conv out t=20 (mixed, per pair)
//   QC  = XC @ Wq[h] + bq  (q rows t<=19)
//   QC2 = XC @ Wq[h]^T     (for his-row x cdd-col scores)
//   QM  = XM @ Wq[h] + bq  (q row t=20)
//   BQC[h][m] = bq[h].XC[m] (bias term for CR2)
//   score blocks (all precomputed, main attn kernel is load+softmax+PV):
//     SCC = QC.XC^T, CR1 = QC.XH^T, CR2 = XH.QC2^T + BQC,
//     SRC = QM.XC^T, SCX = QC.XM^T,
//     SHX[bh][h][25][25] = [XH@Wq+bq ; QM rows] . [XH ; XM rows]^T (fused in k_shx)
//   xv = x @ Wv_r + bv (bias fold exact: softmax rows sum to 1)
//   VAL = P @ xv per head; word-attn k=tanh(VAL@Wk+bk), w=softmax(k.qw*SCALE),
//   REP = w^T VAL; final: mean over HIS, .Wl+bl, log_softmax over CDD.
// ---------------------------------------------------------------------------

#define SCALE_C 0.05773502691896258f   // 1/sqrt(300)

// -------- static workspace (floats) --------
static constexpr long OFF_XC   = 0L;          // 80*20*256      = 409600
static constexpr long OFF_XH   = 409600L;     // 800*20*256     = 4096000
static constexpr long OFF_XM   = 4505600L;    // 4000*256       = 1024000
static constexpr long OFF_QC   = 5529600L;    // 16*1600*256    = 6553600
static constexpr long OFF_QC2  = 12083200L;   // 16*1600*256    = 6553600
static constexpr long OFF_QM   = 18636800L;   // 16*4000*256    = 16384000
static constexpr long OFF_BQC  = 35020800L;   // 16*1600        = 25600
static constexpr long OFF_WVR  = 35046400L;   // 256*256        = 65536
static constexpr long OFF_XVC  = 35111936L;   // 1600*256       = 409600
static constexpr long OFF_XVH  = 35521536L;   // 16000*256      = 4096000
static constexpr long OFF_XVM  = 39617536L;   // 4000*256       = 1024000
static constexpr long OFF_SCC  = 40641536L;   // 256*100*100    = 2560000
static constexpr long OFF_CR1  = 43201536L;   // 256*100*1000   = 25600000
static constexpr long OFF_CR2  = 68801536L;   // 256*1000*100   = 25600000
static constexpr long OFF_SRC  = 94401536L;   // 1280*50*20     = 1280000
static constexpr long OFF_SCX  = 95681536L;   // 1280*20*50     = 1280000
static constexpr long OFF_SHX  = 96961536L;   // 12800*625      = 8000000
static constexpr long OFF_VAL  = 104961536L;  // 4000*41*256    = 41984000
static constexpr long OFF_REP  = 146945536L;  // 4000*256       = 1024000
static constexpr long TOTAL_F  = 147969536L;  // ~592 MB

__device__ __align__(16) float g_buf[TOTAL_F];

// -------- Wv rearrange: WVR[g][h*16+d] = Wv[h][g][d] --------
__global__ __launch_bounds__(256) void k_wvr(const float* __restrict__ Wv)
{
    int i = blockIdx.x * 256 + threadIdx.x;      // 65536
    int g = i >> 8, n = i & 255;
    int h = n >> 4, d = n & 15;
    g_buf[OFF_WVR + i] = Wv[((long)h * 256 + g) * 16 + d];
}

// -------- conv (k=3, SAME, relu).  types: A=cdd rows, B=his rows, C=mixed row 20
__global__ __launch_bounds__(256) void k_conv(const int* __restrict__ cand,
                                              const int* __restrict__ clk,
                                              const float* __restrict__ emb,
                                              const float* __restrict__ W,
                                              const float* __restrict__ cbias)
{
    __shared__ float se[22][300];
    const int bid = blockIdx.x, tid = threadIdx.x;
    int type, nrows, nctx;
    int b = 0, bc = 0, bh = 0, h0 = 0;
    if (bid < 80)       { type = 0; bc = bid;      b = bc / 5; nrows = 20; nctx = 22; }
    else if (bid < 880) { type = 1; bh = bid - 80;             nrows = 20; nctx = 22; }
    else { type = 2; int g = bid - 880; bc = g / 5; h0 = (g % 5) * 10; b = bc / 5; nrows = 10; nctx = 12; }

    for (int f = tid; f < nctx * 300; f += 256) {
        int r = f / 300, e = f - r * 300;
        int tok;
        if (type == 0)      tok = (r < 20) ? cand[bc * 20 + r] : (r == 20 ? 1 : -1);
        else if (type == 1) tok = (r == 0) ? 1 : (r <= 20 ? clk[bh * 20 + r - 1] : -1);
        else                tok = (r == 0) ? cand[bc * 20 + 19] : (r == 1 ? 1 : clk[((b * 50) + h0 + (r - 2)) * 20]);
        se[r][e] = (tok < 0) ? 0.0f : emb[(long)tok * 300 + e];
    }
    __syncthreads();

    const int lane = tid & 63, w = tid >> 6;
    int co[5][3];
    #pragma unroll
    for (int q = 0; q < 5; ++q) {
        int r = w + 4 * q; int rr = (r < nrows) ? r : 0;
        #pragma unroll
        for (int dt = 0; dt < 3; ++dt) {
            int idx;
            if (type == 0)      idx = (rr + dt == 0) ? 21 : rr + dt - 1;
            else if (type == 1) idx = rr + dt;
            else                idx = (dt == 0) ? 0 : (dt == 1 ? 1 : 2 + rr);
            co[q][dt] = idx;
        }
    }
    float acc[5][4] = {};
    for (int dt = 0; dt < 3; ++dt) {
        const float* wb = W + (long)(dt * 300) * 256 + lane * 4;
        for (int e = 0; e < 300; ++e) {
            float4 w4 = *(const float4*)(wb + (long)e * 256);
            #pragma unroll
            for (int q = 0; q < 5; ++q) {
                float a = se[co[q][dt]][e];
                acc[q][0] = fmaf(a, w4.x, acc[q][0]);
                acc[q][1] = fmaf(a, w4.y, acc[q][1]);
                acc[q][2] = fmaf(a, w4.z, acc[q][2]);
                acc[q][3] = fmaf(a, w4.w, acc[q][3]);
            }
        }
    }
    float4 b4 = *(const float4*)&cbias[lane * 4];
    #pragma unroll
    for (int q = 0; q < 5; ++q) {
        int r = w + 4 * q;
        if (r < nrows) {
            float4 o;
            o.x = fmaxf(acc[q][0] + b4.x, 0.f);
            o.y = fmaxf(acc[q][1] + b4.y, 0.f);
            o.z = fmaxf(acc[q][2] + b4.z, 0.f);
            o.w = fmaxf(acc[q][3] + b4.w, 0.f);
            long row;
            if (type == 0)      row = OFF_XC + ((long)bc * 20 + r) * 256;
            else if (type == 1) row = OFF_XH + ((long)bh * 20 + r) * 256;
            else                row = OFF_XM + ((long)(bc * 50 + h0 + r)) * 256;
            *(float4*)&g_buf[row + lane * 4] = o;
        }
    }
}

// -------- generic K=256 GEMM, C = A @ B (+colbias), TB: C = A @ B^T --------
// z decomposes as head = z&15, zo = z>>4.  A always in g_buf; B external or g_buf.
template<bool TB>
__global__ __launch_bounds__(256) void gemm_k256(
    long aOff, long aZH, long aZB,
    const float* Bext, long bOff, long bZH, long bZB,
    const float* biasExt, long biasOff, int biasKind, long sZH, long sZB,
    long cOff, long cZ, int ldc, int M, int N)
{
    const int z = blockIdx.z, head = z & 15, zo = z >> 4;
    const float* A = g_buf + aOff + (long)head * aZH + (long)zo * aZB;
    const float* B = (Bext ? Bext : (const float*)(g_buf + bOff)) + (long)head * bZH + (long)zo * bZB;
    const float* bias = nullptr;
    if (biasKind == 1)      bias = biasExt + (long)head * sZH + (long)zo * sZB;
    else if (biasKind == 2) bias = g_buf + biasOff + (long)head * sZH + (long)zo * sZB;
    float* C = g_buf + cOff + (long)z * cZ;

    const int m0 = blockIdx.x << 6, n0 = blockIdx.y << 6;
    __shared__ __align__(16) float As[32][68];
    __shared__ __align__(16) float Bs[32][68];
    const int tid = threadIdx.x;
    const int tx = tid & 15, ty = tid >> 4;
    float acc[4][4] = {};

    for (int kk = 0; kk < 256; kk += 32) {
        {   // stage A transposed: As[k][m]
            int m = tid >> 2, ks = (tid & 3) << 3;
            int row = m0 + m; if (row > M - 1) row = M - 1;
            const float* ap = A + (long)row * 256 + kk + ks;
            float4 v0 = *(const float4*)ap;
            float4 v1 = *(const float4*)(ap + 4);
            As[ks + 0][m] = v0.x; As[ks + 1][m] = v0.y; As[ks + 2][m] = v0.z; As[ks + 3][m] = v0.w;
            As[ks + 4][m] = v1.x; As[ks + 5][m] = v1.y; As[ks + 6][m] = v1.z; As[ks + 7][m] = v1.w;
        }
        if (TB) {   // B rows are N x 256 row-major -> Bs[k][n]
            int n = tid >> 2, ks = (tid & 3) << 3;
            int col = n0 + n; if (col > N - 1) col = N - 1;
            const float* bp = B + (long)col * 256 + kk + ks;
            float4 v0 = *(const float4*)bp;
            float4 v1 = *(const float4*)(bp + 4);
            Bs[ks + 0][n] = v0.x; Bs[ks + 1][n] = v0.y; Bs[ks + 2][n] = v0.z; Bs[ks + 3][n] = v0.w;
            Bs[ks + 4][n] = v1.x; Bs[ks + 5][n] = v1.y; Bs[ks + 6][n] = v1.z; Bs[ks + 7][n] = v1.w;
        } else {    // B is 256 x 256 row-major
            int k = tid >> 3, ns = (tid & 7) << 3;
            const float* bp = B + (long)(kk + k) * 256 + n0 + ns;
            float4 v0 = *(const float4*)bp;
            float4 v1 = *(const float4*)(bp + 4);
            float* d = &Bs[k][ns];
            d[0] = v0.x; d[1] = v0.y; d[2] = v0.z; d[3] = v0.w;
            d[4] = v1.x; d[5] = v1.y; d[6] = v1.z; d[7] = v1.w;
        }
        __syncthreads();
        #pragma unroll
        for (int k = 0; k < 32; ++k) {
            float4 a4 = *(const float4*)&As[k][ty << 2];
            float4 b4 = *(const float4*)&Bs[k][tx << 2];
            float av[4] = {a4.x, a4.y, a4.z, a4.w};
            float bv_[4] = {b4.x, b4.y, b4.z, b4.w};
            #pragma unroll
            for (int i = 0; i < 4; ++i)
                #pragma unroll
                for (int j = 0; j < 4; ++j)
                    acc[i][j] = fmaf(av[i], bv_[j], acc[i][j]);
        }
        __syncthreads();
    }
    float cb[4] = {0.f, 0.f, 0.f, 0.f};
    if (bias) {
        #pragma unroll
        for (int j = 0; j < 4; ++j) { int col = n0 + (tx << 2) + j; if (col < N) cb[j] = bias[col]; }
    }
    #pragma unroll
    for (int i = 0; i < 4; ++i) {
        int row = m0 + (ty << 2) + i;
        if (row < M) {
            #pragma unroll
            for (int j = 0; j < 4; ++j) {
                int col = n0 + (tx << 2) + j;
                if (col < N) C[(long)row * ldc + col] = acc[i][j] + cb[j];
            }
        }
    }
}

// -------- BQC[h][m] = bq[h] . XC[m] --------
__global__ __launch_bounds__(256) void k_bq(const float* __restrict__ bq)
{
    __shared__ float sbq[16][260];
    const int tid = threadIdx.x;
    for (int i = tid; i < 4096; i += 256) sbq[i >> 8][i & 255] = bq[i];
    __syncthreads();
    const int mm = tid >> 4, hh = tid & 15;
    const int m = blockIdx.x * 16 + mm;
    const float* x = &g_buf[OFF_XC + (long)m * 256];
    float s = 0.f;
    for (int g = 0; g < 256; g += 4) {
        float4 xv = *(const float4*)&x[g];
        s = fmaf(sbq[hh][g], xv.x, s);
        s = fmaf(sbq[hh][g + 1], xv.y, s);
        s = fmaf(sbq[hh][g + 2], xv.z, s);
        s = fmaf(sbq[hh][g + 3], xv.w, s);
    }
    g_buf[OFF_BQC + (long)hh * 1600 + m] = s;
}

// -------- fused: per (b,h) compute Q = XH@Wq[h]+bq, extended Gram vs [XH;XM] ----
// SHX[bh][head][25][25]: rows 0..19 = q(t=21..40), rows 20..24 = q(t=20) per c;
//                        cols 0..19 = x(s=21..40), cols 20..24 = x(s=20) per c.
__global__ __launch_bounds__(256) void k_shx(const float* __restrict__ Wq,
                                             const float* __restrict__ bq)
{
    const int bh = blockIdx.x;
    const int b = bh / 50, h = bh % 50;
    __shared__ __align__(16) float sx[25][260];
    __shared__ __align__(16) float sq[25][260];
    __shared__ __align__(16) float swq[16][256];
    const int tid = threadIdx.x;
    for (int i = tid; i < 25 * 256; i += 256) {
        int r = i >> 8, e = i & 255;
        float v;
        if (r < 20) v = g_buf[OFF_XH + ((long)bh * 20 + r) * 256 + e];
        else        v = g_buf[OFF_XM + ((long)((b * 5 + (r - 20)) * 50 + h)) * 256 + e];
        sx[r][e] = v;
    }
    __syncthreads();
    const int tx = tid & 63, ty = tid >> 6;
    for (int head = 0; head < 16; ++head) {
        float acc[5][4] = {};
        for (int kk = 0; kk < 256; kk += 16) {
            __syncthreads();
            {   // stage Wq chunk
                int k = tid >> 4, n16 = (tid & 15) << 4;
                const float4* src = (const float4*)(Wq + ((long)head * 256 + kk + k) * 256 + n16);
                float4* dst = (float4*)&swq[k][n16];
                dst[0] = src[0]; dst[1] = src[1]; dst[2] = src[2]; dst[3] = src[3];
            }
            __syncthreads();
            for (int k = 0; k < 16; ++k) {
                float4 b4 = *(const float4*)&swq[k][tx * 4];
                #pragma unroll
                for (int r = 0; r < 5; ++r) {
                    float a = sx[ty * 5 + r][kk + k];
                    acc[r][0] = fmaf(a, b4.x, acc[r][0]);
                    acc[r][1] = fmaf(a, b4.y, acc[r][1]);
                    acc[r][2] = fmaf(a, b4.z, acc[r][2]);
                    acc[r][3] = fmaf(a, b4.w, acc[r][3]);
                }
            }
        }
        // write q rows (+bias), load QM rows (q at t=20, bias already included)
        #pragma unroll
        for (int r = 0; r < 5; ++r)
            #pragma unroll
            for (int j = 0; j < 4; ++j)
                sq[ty * 5 + r][tx * 4 + j] = acc[r][j] + bq[head * 256 + tx * 4 + j];
        for (int i = tid; i < 5 * 256; i += 256) {
            int r = i >> 8, e = i & 255;
            sq[20 + r][e] = g_buf[OFF_QM + ((long)head * 4000 + (long)(b * 5 + r) * 50 + h) * 256 + e];
        }
        __syncthreads();
        {
            int j = tid & 31, i0 = tid >> 5;
            if (j < 25) {
                for (int i = i0; i < 25; i += 8) {
                    float s = 0.f;
                    for (int k = 0; k < 256; k += 4) {
                        float4 qa = *(const float4*)&sq[i][k];
                        float4 xb = *(const float4*)&sx[j][k];
                        s = fmaf(qa.x, xb.x, fmaf(qa.y, xb.y, fmaf(qa.z, xb.z, fmaf(qa.w, xb.w, s))));
                    }
                    g_buf[OFF_SHX + ((long)bh * 16 + head) * 625 + i * 25 + j] = s;
                }
            }
        }
        __syncthreads();
    }
}

// -------- per-pair attention: assemble scores (pure loads), softmax, P@xv ----
__global__ __launch_bounds__(256) void k_attn()
{
    const int p = blockIdx.x;
    const int b = p / 250;
    const int c = (p / 50) % 5;
    const int h = p % 50;
    const int bc = b * 5 + c;
    const int bh = b * 50 + h;
    __shared__ float ssc[41][44];
    __shared__ float sxv[41][16];
    const int tid = threadIdx.x;
    for (int head = 0; head < 16; ++head) {
        const long z  = b * 16 + head;
        const long zc = bc * 16 + head;
        const long zh = (long)bh * 16 + head;
        for (int i = tid; i < 41 * 16; i += 256) {
            int r = i >> 4, d = i & 15;
            float v;
            if (r < 20)       v = g_buf[OFF_XVC + ((long)bc * 20 + r) * 256 + head * 16 + d];
            else if (r == 20) v = g_buf[OFF_XVM + (long)p * 256 + head * 16 + d];
            else              v = g_buf[OFF_XVH + ((long)bh * 20 + (r - 21)) * 256 + head * 16 + d];
            sxv[r][d] = v;
        }
        for (int i = tid; i < 1681; i += 256) {
            int t = i / 41, s = i - t * 41;
            float v;
            if (t < 20) {
                if (s < 20)       v = g_buf[OFF_SCC + z * 10000 + (c * 20 + t) * 100 + (c * 20 + s)];
                else if (s == 20) v = g_buf[OFF_SCX + zc * 1000 + t * 50 + h];
                else              v = g_buf[OFF_CR1 + z * 100000 + (long)(c * 20 + t) * 1000 + h * 20 + (s - 21)];
            } else if (t == 20) {
                if (s < 20)       v = g_buf[OFF_SRC + zc * 1000 + h * 20 + s];
                else              v = g_buf[OFF_SHX + zh * 625 + (20 + c) * 25 + ((s == 20) ? (20 + c) : (s - 21))];
            } else {
                if (s < 20)       v = g_buf[OFF_CR2 + z * 100000 + (long)(h * 20 + (t - 21)) * 100 + (c * 20 + s)];
                else              v = g_buf[OFF_SHX + zh * 625 + (t - 21) * 25 + ((s == 20) ? (20 + c) : (s - 21))];
            }
            ssc[t][s] = v * SCALE_C;
        }
        __syncthreads();
        if (tid < 41) {
            float m = -1e30f;
            for (int s2 = 0; s2 < 41; ++s2) m = fmaxf(m, ssc[tid][s2]);
            float sum = 0.f;
            for (int s2 = 0; s2 < 41; ++s2) { float e = __expf(ssc[tid][s2] - m); ssc[tid][s2] = e; sum += e; }
            float inv = 1.f / sum;
            for (int s2 = 0; s2 < 41; ++s2) ssc[tid][s2] *= inv;
        }
        __syncthreads();
        {
            const int t0 = tid >> 4, d = tid & 15;
            for (int t = t0; t < 41; t += 16) {
                float a = 0.f;
                for (int s2 = 0; s2 < 41; ++s2) a = fmaf(ssc[t][s2], sxv[s2][d], a);
                g_buf[OFF_VAL + ((long)p * 41 + t) * 256 + head * 16 + d] = a;
            }
        }
        __syncthreads();
    }
}

// -------- word attention per pair: k=tanh(VAL@Wk+bk); w=softmax(k.qw*SCALE); REP=w^T VAL
__global__ __launch_bounds__(256) void k_wa(const float* __restrict__ Wk,
                                            const float* __restrict__ bk,
                                            const float* __restrict__ qw)
{
    const int p = blockIdx.x, tid = threadIdx.x;
    __shared__ __align__(16) float sval[41 * 256];
    __shared__ float skq[41];
    for (int i = tid; i < 41 * 256; i += 256) sval[i] = g_buf[OFF_VAL + (long)p * 41 * 256 + i];
    __syncthreads();
    const int tx = tid & 63, ty = tid >> 6;
    float acc[11][4] = {};
    for (int dd = 0; dd < 256; ++dd) {
        const float* wr = Wk + (long)dd * 200;
        float w0 = (tx < 200)       ? wr[tx]        : 0.f;
        float w1 = (tx + 64 < 200)  ? wr[tx + 64]   : 0.f;
        float w2 = (tx + 128 < 200) ? wr[tx + 128]  : 0.f;
        float w3 = (tx + 192 < 200) ? wr[tx + 192]  : 0.f;
        #pragma unroll
        for (int k = 0; k < 11; ++k) {
            int t = ty + 4 * k;
            if (t < 41) {
                float a = sval[t * 256 + dd];
                acc[k][0] = fmaf(a, w0, acc[k][0]);
                acc[k][1] = fmaf(a, w1, acc[k][1]);
                acc[k][2] = fmaf(a, w2, acc[k][2]);
                acc[k][3] = fmaf(a, w3, acc[k][3]);
            }
        }
    }
    #pragma unroll
    for (int k = 0; k < 11; ++k) {
        int t = ty + 4 * k;
        float s = 0.f;
        if (t < 41) {
            if (tx < 200)       s += tanhf(acc[k][0] + bk[tx])       * qw[tx];
            if (tx + 64 < 200)  s += tanhf(acc[k][1] + bk[tx + 64])  * qw[tx + 64];
            if (tx + 128 < 200) s += tanhf(acc[k][2] + bk[tx + 128]) * qw[tx + 128];
            if (tx + 192 < 200) s += tanhf(acc[k][3] + bk[tx + 192]) * qw[tx + 192];
        }
        #pragma unroll
        for (int off = 32; off > 0; off >>= 1) s += __shfl_down(s, off, 64);
        if (tx == 0 && t < 41) skq[t] = s;
    }
    __syncthreads();
    if (tid < 64) {
        float v = (tid < 41) ? skq[tid] * SCALE_C : -1e30f;
        float m = v;
        #pragma unroll
        for (int off = 32; off > 0; off >>= 1) m = fmaxf(m, __shfl_xor(m, off, 64));
        float e = (tid < 41) ? __expf(v - m) : 0.f;
        float sum = e;
        #pragma unroll
        for (int off = 32; off > 0; off >>= 1) sum += __shfl_xor(sum, off, 64);
        if (tid < 41) skq[tid] = e / sum;
    }
    __syncthreads();
    {
        float r = 0.f;
        for (int t = 0; t < 41; ++t) r = fmaf(skq[t], sval[t * 256 + tid], r);
        g_buf[OFF_REP + (long)p * 256 + tid] = r;
    }
}

// -------- final: mean over HIS, .Wl + bl, log_softmax over CDD --------
__global__ __launch_bounds__(256) void k_final(const float* __restrict__ Wl,
                                               const float* __restrict__ bl,
                                               float* __restrict__ out)
{
    const int b = blockIdx.x, tid = threadIdx.x;
    __shared__ float ssum[4];
    __shared__ float sc5[5];
    float wl = Wl[tid];
    for (int c = 0; c < 5; ++c) {
        float fv = 0.f;
        const long base = OFF_REP + ((long)(b * 5 + c) * 50) * 256 + tid;
        for (int h = 0; h < 50; ++h) fv += g_buf[base + (long)h * 256];
        float v = fv * (1.0f / 50.0f) * wl;
        #pragma unroll
        for (int off = 32; off > 0; off >>= 1) v += __shfl_down(v, off, 64);
        if ((tid & 63) == 0) ssum[tid >> 6] = v;
        __syncthreads();
        if (tid == 0) sc5[c] = ssum[0] + ssum[1] + ssum[2] + ssum[3] + bl[0];
        __syncthreads();
    }
    if (tid == 0) {
        float m = -1e30f;
        for (int c = 0; c < 5; ++c) m = fmaxf(m, sc5[c]);
        float sum = 0.f;
        for (int c = 0; c < 5; ++c) sum += expf(sc5[c] - m);
        float lse = m + logf(sum);
        for (int c = 0; c < 5; ++c) out[b * 5 + c] = sc5[c] - lse;
    }
}

extern "C" void kernel_launch(void* const* d_in, const int* in_sizes, int n_in,
                              void* d_out, int out_size, void* d_ws, size_t ws_size,
                              hipStream_t stream)
{
    (void)in_sizes; (void)n_in; (void)d_ws; (void)ws_size; (void)out_size;
    const int*   cand  = (const int*)d_in[0];
    const int*   clk   = (const int*)d_in[1];
    const float* emb   = (const float*)d_in[2];
    const float* convw = (const float*)d_in[3];
    const float* convb = (const float*)d_in[4];
    const float* Wq    = (const float*)d_in[5];
    const float* bq    = (const float*)d_in[6];
    const float* Wv    = (const float*)d_in[7];
    const float* bv    = (const float*)d_in[8];
    const float* Wk    = (const float*)d_in[9];
    const float* bk    = (const float*)d_in[10];
    const float* qw    = (const float*)d_in[11];
    const float* Wl    = (const float*)d_in[12];
    const float* bl    = (const float*)d_in[13];
    float* out = (float*)d_out;

    k_wvr <<<256, 256, 0, stream>>>(Wv);
    k_conv<<<1280, 256, 0, stream>>>(cand, clk, emb, convw, convb);

    // projections (K=256 GEMMs)
    gemm_k256<false><<<dim3(25, 4, 16), 256, 0, stream>>>(
        OFF_XC, 0, 0,  Wq, 0, 65536, 0,  bq, 0, 1, 256, 0,  OFF_QC, 409600, 256, 1600, 256);
    gemm_k256<true ><<<dim3(25, 4, 16), 256, 0, stream>>>(
        OFF_XC, 0, 0,  Wq, 0, 65536, 0,  nullptr, 0, 0, 0, 0,  OFF_QC2, 409600, 256, 1600, 256);
    gemm_k256<false><<<dim3(63, 4, 16), 256, 0, stream>>>(
        OFF_XM, 0, 0,  Wq, 0, 65536, 0,  bq, 0, 1, 256, 0,  OFF_QM, 1024000, 256, 4000, 256);
    gemm_k256<false><<<dim3(25, 4, 1), 256, 0, stream>>>(
        OFF_XC, 0, 0,  nullptr, OFF_WVR, 0, 0,  bv, 0, 1, 0, 0,  OFF_XVC, 0, 256, 1600, 256);
    gemm_k256<false><<<dim3(250, 4, 1), 256, 0, stream>>>(
        OFF_XH, 0, 0,  nullptr, OFF_WVR, 0, 0,  bv, 0, 1, 0, 0,  OFF_XVH, 0, 256, 16000, 256);
    gemm_k256<false><<<dim3(63, 4, 1), 256, 0, stream>>>(
        OFF_XM, 0, 0,  nullptr, OFF_WVR, 0, 0,  bv, 0, 1, 0, 0,  OFF_XVM, 0, 256, 4000, 256);
    k_bq<<<100, 256, 0, stream>>>(bq);

    // score blocks (NT GEMMs)
    gemm_k256<true><<<dim3(2, 2, 256), 256, 0, stream>>>(
        OFF_QC, 409600, 25600,  nullptr, OFF_XC, 0, 25600,  nullptr, 0, 0, 0, 0,
        OFF_SCC, 10000, 100, 100, 100);
    gemm_k256<true><<<dim3(2, 16, 256), 256, 0, stream>>>(
        OFF_QC, 409600, 25600,  nullptr, OFF_XH, 0, 256000,  nullptr, 0, 0, 0, 0,
        OFF_CR1, 100000, 1000, 100, 1000);
    gemm_k256<true><<<dim3(16, 2, 256), 256, 0, stream>>>(
        OFF_XH, 0, 256000,  nullptr, OFF_QC2, 409600, 25600,  nullptr, OFF_BQC, 2, 1600, 100,
        OFF_CR2, 100000, 100, 1000, 100);
    gemm_k256<true><<<dim3(1, 1, 1280), 256, 0, stream>>>(
        OFF_QM, 1024000, 12800,  nullptr, OFF_XC, 0, 5120,  nullptr, 0, 0, 0, 0,
        OFF_SRC, 1000, 20, 50, 20);
    gemm_k256<true><<<dim3(1, 1, 1280), 256, 0, stream>>>(
        OFF_QC, 409600, 5120,  nullptr, OFF_XM, 0, 12800,  nullptr, 0, 0, 0, 0,
        OFF_SCX, 1000, 50, 20, 50);
    k_shx<<<800, 256, 0, stream>>>(Wq, bq);

    k_attn <<<4000, 256, 0, stream>>>();
    k_wa   <<<4000, 256, 0, stream>>>(Wk, bk, qw);
    k_final<<<16, 256, 0, stream>>>(Wl, bl, out);
}

// Round 2
// 3167.198 us; speedup vs baseline: 1.0040x; 1.0040x over previous
//
#include <hip/hip_runtime.h>
#include <hip/hip_bf16.h>
#include <math.h>

// ---------------------------------------------------------------------------
// GCAModel forward, decomposed (all f32 this round):
//   B=16 CDD=5 HIS=50 S=20 T=41 E=300 F=256 H=16 DV=16 QD=200
//   fusion = [cdd(0..19) | SEP@20 | his(21..40)]
// Sharing exploited:
//   XC [80][20][256]  : conv out t=0..19 (cdd-only, per (b,c))
//   XH [800][20][256] : conv out t=21..40 (his-only, per (b,h))
//   XM [4000][256]    : conv out t=20 (mixed, per pair)
//   QC  = XC @ Wq[h] + bq  (q rows t<=19)
//   QC2 = XC @ Wq[h]^T     (for his-row x cdd-col scores)
//   QM  = XM @ Wq[h] + bq  (q row t=20)
//   BQC[h][m] = bq[h].XC[m] (bias term for CR2)
//   score blocks (all precomputed, main attn kernel is load+softmax+PV):
//     SCC = QC.XC^T, CR1 = QC.XH^T, CR2 = XH.QC2^T + BQC,
//     SRC = QM.XC^T, SCX = QC.XM^T,
//     SHX[bh][h][25][25] = [XH@Wq+bq ; QM rows] . [XH ; XM rows]^T (fused in k_shx)
//   xv = x @ Wv_r + bv (bias fold exact: softmax rows sum to 1)
//   VAL = P @ xv per head; word-attn k=tanh(VAL@Wk+bk), w=softmax(k.qw*SCALE),
//   REP = w^T VAL; final: mean over HIS, .Wl+bl, log_softmax over CDD.
// ---------------------------------------------------------------------------

#define SCALE_C 0.05773502691896258f   // 1/sqrt(300)

// -------- static workspace (floats) --------
static constexpr long OFF_XC   = 0L;          // 80*20*256      = 409600
static constexpr long OFF_XH   = 409600L;     // 800*20*256     = 4096000
static constexpr long OFF_XM   = 4505600L;    // 4000*256       = 1024000
static constexpr long OFF_QC   = 5529600L;    // 16*1600*256    = 6553600
static constexpr long OFF_QC2  = 12083200L;   // 16*1600*256    = 6553600
static constexpr long OFF_QM   = 18636800L;   // 16*4000*256    = 16384000
static constexpr long OFF_BQC  = 35020800L;   // 16*1600        = 25600
static constexpr long OFF_WVR  = 35046400L;   // 256*256        = 65536
static constexpr long OFF_XVC  = 35111936L;   // 1600*256       = 409600
static constexpr long OFF_XVH  = 35521536L;   // 16000*256      = 4096000
static constexpr long OFF_XVM  = 39617536L;   // 4000*256       = 1024000
static constexpr long OFF_SCC  = 40641536L;   // 256*100*100    = 2560000
static constexpr long OFF_CR1  = 43201536L;   // 256*100*1000   = 25600000
static constexpr long OFF_CR2  = 68801536L;   // 256*1000*100   = 25600000
static constexpr long OFF_SRC  = 94401536L;   // 1280*50*20     = 1280000
static constexpr long OFF_SCX  = 95681536L;   // 1280*20*50     = 1280000
static constexpr long OFF_SHX  = 96961536L;   // 12800*625      = 8000000
static constexpr long OFF_VAL  = 104961536L;  // 4000*41*256    = 41984000
static constexpr long OFF_REP  = 146945536L;  // 4000*256       = 1024000
static constexpr long TOTAL_F  = 147969536L;  // ~592 MB

__device__ __align__(16) float g_buf[TOTAL_F];

// -------- Wv rearrange: WVR[g][h*16+d] = Wv[h][g][d] --------
__global__ __launch_bounds__(256) void k_wvr(const float* __restrict__ Wv)
{
    int i = blockIdx.x * 256 + threadIdx.x;      // 65536
    int g = i >> 8, n = i & 255;
    int h = n >> 4, d = n & 15;
    g_buf[OFF_WVR + i] = Wv[((long)h * 256 + g) * 16 + d];
}

// -------- conv (k=3, SAME, relu).  types: A=cdd rows, B=his rows, C=mixed row 20
__global__ __launch_bounds__(256) void k_conv(const int* __restrict__ cand,
                                              const int* __restrict__ clk,
                                              const float* __restrict__ emb,
                                              const float* __restrict__ W,
                                              const float* __restrict__ cbias)
{
    __shared__ float se[22][300];
    const int bid = blockIdx.x, tid = threadIdx.x;
    int type, nrows, nctx;
    int b = 0, bc = 0, bh = 0, h0 = 0;
    if (bid < 80)       { type = 0; bc = bid;      b = bc / 5; nrows = 20; nctx = 22; }
    else if (bid < 880) { type = 1; bh = bid - 80;             nrows = 20; nctx = 22; }
    else { type = 2; int g = bid - 880; bc = g / 5; h0 = (g % 5) * 10; b = bc / 5; nrows = 10; nctx = 12; }

    for (int f = tid; f < nctx * 300; f += 256) {
        int r = f / 300, e = f - r * 300;
        int tok;
        if (type == 0)      tok = (r < 20) ? cand[bc * 20 + r] : (r == 20 ? 1 : -1);
        else if (type == 1) tok = (r == 0) ? 1 : (r <= 20 ? clk[bh * 20 + r - 1] : -1);
        else                tok = (r == 0) ? cand[bc * 20 + 19] : (r == 1 ? 1 : clk[((b * 50) + h0 + (r - 2)) * 20]);
        se[r][e] = (tok < 0) ? 0.0f : emb[(long)tok * 300 + e];
    }
    __syncthreads();

    const int lane = tid & 63, w = tid >> 6;
    int co[5][3];
    #pragma unroll
    for (int q = 0; q < 5; ++q) {
        int r = w + 4 * q; int rr = (r < nrows) ? r : 0;
        #pragma unroll
        for (int dt = 0; dt < 3; ++dt) {
            int idx;
            if (type == 0)      idx = (rr + dt == 0) ? 21 : rr + dt - 1;
            else if (type == 1) idx = rr + dt;
            else                idx = (dt == 0) ? 0 : (dt == 1 ? 1 : 2 + rr);
            co[q][dt] = idx;
        }
    }
    float acc[5][4] = {};
    for (int dt = 0; dt < 3; ++dt) {
        const float* wb = W + (long)(dt * 300) * 256 + lane * 4;
        for (int e = 0; e < 300; ++e) {
            float4 w4 = *(const float4*)(wb + (long)e * 256);
            #pragma unroll
            for (int q = 0; q < 5; ++q) {
                float a = se[co[q][dt]][e];
                acc[q][0] = fmaf(a, w4.x, acc[q][0]);
                acc[q][1] = fmaf(a, w4.y, acc[q][1]);
                acc[q][2] = fmaf(a, w4.z, acc[q][2]);
                acc[q][3] = fmaf(a, w4.w, acc[q][3]);
            }
        }
    }
    float4 b4 = *(const float4*)&cbias[lane * 4];
    #pragma unroll
    for (int q = 0; q < 5; ++q) {
        int r = w + 4 * q;
        if (r < nrows) {
            float4 o;
            o.x = fmaxf(acc[q][0] + b4.x, 0.f);
            o.y = fmaxf(acc[q][1] + b4.y, 0.f);
            o.z = fmaxf(acc[q][2] + b4.z, 0.f);
            o.w = fmaxf(acc[q][3] + b4.w, 0.f);
            long row;
            if (type == 0)      row = OFF_XC + ((long)bc * 20 + r) * 256;
            else if (type == 1) row = OFF_XH + ((long)bh * 20 + r) * 256;
            else                row = OFF_XM + ((long)(bc * 50 + h0 + r)) * 256;
            *(float4*)&g_buf[row + lane * 4] = o;
        }
    }
}

// -------- generic K=256 GEMM, C = A @ B (+colbias), TB: C = A @ B^T --------
// z decomposes as head = z&15, zo = z>>4.  A always in g_buf; B external or g_buf.
template<bool TB>
__global__ __launch_bounds__(256) void gemm_k256(
    long aOff, long aZH, long aZB,
    const float* Bext, long bOff, long bZH, long bZB,
    const float* biasExt, long biasOff, int biasKind, long sZH, long sZB,
    long cOff, long cZ, int ldc, int M, int N)
{
    const int z = blockIdx.z, head = z & 15, zo = z >> 4;
    const float* A = g_buf + aOff + (long)head * aZH + (long)zo * aZB;
    const float* B = (Bext ? Bext : (const float*)(g_buf + bOff)) + (long)head * bZH + (long)zo * bZB;
    const float* bias = nullptr;
    if (biasKind == 1)      bias = biasExt + (long)head * sZH + (long)zo * sZB;
    else if (biasKind == 2) bias = g_buf + biasOff + (long)head * sZH + (long)zo * sZB;
    float* C = g_buf + cOff + (long)z * cZ;

    const int m0 = blockIdx.x << 6, n0 = blockIdx.y << 6;
    __shared__ __align__(16) float As[32][68];
    __shared__ __align__(16) float Bs[32][68];
    const int tid = threadIdx.x;
    const int tx = tid & 15, ty = tid >> 4;
    float acc[4][4] = {};

    for (int kk = 0; kk < 256; kk += 32) {
        {   // stage A transposed: As[k][m]
            int m = tid >> 2, ks = (tid & 3) << 3;
            int row = m0 + m; if (row > M - 1) row = M - 1;
            const float* ap = A + (long)row * 256 + kk + ks;
            float4 v0 = *(const float4*)ap;
            float4 v1 = *(const float4*)(ap + 4);
            As[ks + 0][m] = v0.x; As[ks + 1][m] = v0.y; As[ks + 2][m] = v0.z; As[ks + 3][m] = v0.w;
            As[ks + 4][m] = v1.x; As[ks + 5][m] = v1.y; As[ks + 6][m] = v1.z; As[ks + 7][m] = v1.w;
        }
        if (TB) {   // B rows are N x 256 row-major -> Bs[k][n]
            int n = tid >> 2, ks = (tid & 3) << 3;
            int col = n0 + n; if (col > N - 1) col = N - 1;
            const float* bp = B + (long)col * 256 + kk + ks;
            float4 v0 = *(const float4*)bp;
            float4 v1 = *(const float4*)(bp + 4);
            Bs[ks + 0][n] = v0.x; Bs[ks + 1][n] = v0.y; Bs[ks + 2][n] = v0.z; Bs[ks + 3][n] = v0.w;
            Bs[ks + 4][n] = v1.x; Bs[ks + 5][n] = v1.y; Bs[ks + 6][n] = v1.z; Bs[ks + 7][n] = v1.w;
        } else {    // B is 256 x 256 row-major
            int k = tid >> 3, ns = (tid & 7) << 3;
            const float* bp = B + (long)(kk + k) * 256 + n0 + ns;
            float4 v0 = *(const float4*)bp;
            float4 v1 = *(const float4*)(bp + 4);
            float* d = &Bs[k][ns];
            d[0] = v0.x; d[1] = v0.y; d[2] = v0.z; d[3] = v0.w;
            d[4] = v1.x; d[5] = v1.y; d[6] = v1.z; d[7] = v1.w;
        }
        __syncthreads();
        #pragma unroll
        for (int k = 0; k < 32; ++k) {
            float4 a4 = *(const float4*)&As[k][ty << 2];
            float4 b4 = *(const float4*)&Bs[k][tx << 2];
            float av[4] = {a4.x, a4.y, a4.z, a4.w};
            float bv_[4] = {b4.x, b4.y, b4.z, b4.w};
            #pragma unroll
            for (int i = 0; i < 4; ++i)
                #pragma unroll
                for (int j = 0; j < 4; ++j)
                    acc[i][j] = fmaf(av[i], bv_[j], acc[i][j]);
        }
        __syncthreads();
    }
    float cb[4] = {0.f, 0.f, 0.f, 0.f};
    if (bias) {
        #pragma unroll
        for (int j = 0; j < 4; ++j) { int col = n0 + (tx << 2) + j; if (col < N) cb[j] = bias[col]; }
    }
    #pragma unroll
    for (int i = 0; i < 4; ++i) {
        int row = m0 + (ty << 2) + i;
        if (row < M) {
            #pragma unroll
            for (int j = 0; j < 4; ++j) {
                int col = n0 + (tx << 2) + j;
                if (col < N) C[(long)row * ldc + col] = acc[i][j] + cb[j];
            }
        }
    }
}

// -------- BQC[h][m] = bq[h] . XC[m] --------
__global__ __launch_bounds__(256) void k_bq(const float* __restrict__ bq)
{
    __shared__ float sbq[16][260];
    const int tid = threadIdx.x;
    for (int i = tid; i < 4096; i += 256) sbq[i >> 8][i & 255] = bq[i];
    __syncthreads();
    const int mm = tid >> 4, hh = tid & 15;
    const int m = blockIdx.x * 16 + mm;
    const float* x = &g_buf[OFF_XC + (long)m * 256];
    float s = 0.f;
    for (int g = 0; g < 256; g += 4) {
        float4 xv = *(const float4*)&x[g];
        s = fmaf(sbq[hh][g], xv.x, s);
        s = fmaf(sbq[hh][g + 1], xv.y, s);
        s = fmaf(sbq[hh][g + 2], xv.z, s);
        s = fmaf(sbq[hh][g + 3], xv.w, s);
    }
    g_buf[OFF_BQC + (long)hh * 1600 + m] = s;
}

// -------- fused: per (b,h) compute Q = XH@Wq[h]+bq, extended Gram vs [XH;XM] ----
// SHX[bh][head][25][25]: rows 0..19 = q(t=21..40), rows 20..24 = q(t=20) per c;
//                        cols 0..19 = x(s=21..40), cols 20..24 = x(s=20) per c.
__global__ __launch_bounds__(256) void k_shx(const float* __restrict__ Wq,
                                             const float* __restrict__ bq)
{
    const int bh = blockIdx.x;
    const int b = bh / 50, h = bh % 50;
    __shared__ __align__(16) float sx[25][260];
    __shared__ __align__(16) float sq[25][260];
    __shared__ __align__(16) float swq[16][256];
    const int tid = threadIdx.x;
    for (int i = tid; i < 25 * 256; i += 256) {
        int r = i >> 8, e = i & 255;
        float v;
        if (r < 20) v = g_buf[OFF_XH + ((long)bh * 20 + r) * 256 + e];
        else        v = g_buf[OFF_XM + ((long)((b * 5 + (r - 20)) * 50 + h)) * 256 + e];
        sx[r][e] = v;
    }
    __syncthreads();
    const int tx = tid & 63, ty = tid >> 6;
    for (int head = 0; head < 16; ++head) {
        float acc[5][4] = {};
        for (int kk = 0; kk < 256; kk += 16) {
            __syncthreads();
            {   // stage Wq chunk
                int k = tid >> 4, n16 = (tid & 15) << 4;
                const float4* src = (const float4*)(Wq + ((long)head * 256 + kk + k) * 256 + n16);
                float4* dst = (float4*)&swq[k][n16];
                dst[0] = src[0]; dst[1] = src[1]; dst[2] = src[2]; dst[3] = src[3];
            }
            __syncthreads();
            for (int k = 0; k < 16; ++k) {
                float4 b4 = *(const float4*)&swq[k][tx * 4];
                #pragma unroll
                for (int r = 0; r < 5; ++r) {
                    float a = sx[ty * 5 + r][kk + k];
                    acc[r][0] = fmaf(a, b4.x, acc[r][0]);
                    acc[r][1] = fmaf(a, b4.y, acc[r][1]);
                    acc[r][2] = fmaf(a, b4.z, acc[r][2]);
                    acc[r][3] = fmaf(a, b4.w, acc[r][3]);
                }
            }
        }
        // write q rows (+bias), load QM rows (q at t=20, bias already included)
        #pragma unroll
        for (int r = 0; r < 5; ++r)
            #pragma unroll
            for (int j = 0; j < 4; ++j)
                sq[ty * 5 + r][tx * 4 + j] = acc[r][j] + bq[head * 256 + tx * 4 + j];
        for (int i = tid; i < 5 * 256; i += 256) {
            int r = i >> 8, e = i & 255;
            sq[20 + r][e] = g_buf[OFF_QM + ((long)head * 4000 + (long)(b * 5 + r) * 50 + h) * 256 + e];
        }
        __syncthreads();
        {
            int j = tid & 31, i0 = tid >> 5;
            if (j < 25) {
                for (int i = i0; i < 25; i += 8) {
                    float s = 0.f;
                    for (int k = 0; k < 256; k += 4) {
                        float4 qa = *(const float4*)&sq[i][k];
                        float4 xb = *(const float4*)&sx[j][k];
                        s = fmaf(qa.x, xb.x, fmaf(qa.y, xb.y, fmaf(qa.z, xb.z, fmaf(qa.w, xb.w, s))));
                    }
                    g_buf[OFF_SHX + ((long)bh * 16 + head) * 625 + i * 25 + j] = s;
                }
            }
        }
        __syncthreads();
    }
}

// -------- per-pair attention: assemble scores (pure loads), softmax, P@xv ----
__global__ __launch_bounds__(256) void k_attn()
{
    const int p = blockIdx.x;
    const int b = p / 250;
    const int c = (p / 50) % 5;
    const int h = p % 50;
    const int bc = b * 5 + c;
    const int bh = b * 50 + h;
    __shared__ float ssc[41][44];
    __shared__ float sxv[41][16];
    const int tid = threadIdx.x;
    for (int head = 0; head < 16; ++head) {
        const long z  = b * 16 + head;
        const long zc = bc * 16 + head;
        const long zh = (long)bh * 16 + head;
        for (int i = tid; i < 41 * 16; i += 256) {
            int r = i >> 4, d = i & 15;
            float v;
            if (r < 20)       v = g_buf[OFF_XVC + ((long)bc * 20 + r) * 256 + head * 16 + d];
            else if (r == 20) v = g_buf[OFF_XVM + (long)p * 256 + head * 16 + d];
            else              v = g_buf[OFF_XVH + ((long)bh * 20 + (r - 21)) * 256 + head * 16 + d];
            sxv[r][d] = v;
        }
        for (int i = tid; i < 1681; i += 256) {
            int t = i / 41, s = i - t * 41;
            float v;
            if (t < 20) {
                if (s < 20)       v = g_buf[OFF_SCC + z * 10000 + (c * 20 + t) * 100 + (c * 20 + s)];
                else if (s == 20) v = g_buf[OFF_SCX + zc * 1000 + t * 50 + h];
                else              v = g_buf[OFF_CR1 + z * 100000 + (long)(c * 20 + t) * 1000 + h * 20 + (s - 21)];
            } else if (t == 20) {
                if (s < 20)       v = g_buf[OFF_SRC + zc * 1000 + h * 20 + s];
                else              v = g_buf[OFF_SHX + zh * 625 + (20 + c) * 25 + ((s == 20) ? (20 + c) : (s - 21))];
            } else {
                if (s < 20)       v = g_buf[OFF_CR2 + z * 100000 + (long)(h * 20 + (t - 21)) * 100 + (c * 20 + s)];
                else              v = g_buf[OFF_SHX + zh * 625 + (t - 21) * 25 + ((s == 20) ? (20 + c) : (s - 21))];
            }
            ssc[t][s] = v * SCALE_C;
        }
        __syncthreads();
        if (tid < 41) {
            float m = -1e30f;
            for (int s2 = 0; s2 < 41; ++s2) m = fmaxf(m, ssc[tid][s2]);
            float sum = 0.f;
            for (int s2 = 0; s2 < 41; ++s2) { float e = __expf(ssc[tid][s2] - m); ssc[tid][s2] = e; sum += e; }
            float inv = 1.f / sum;
            for (int s2 = 0; s2 < 41; ++s2) ssc[tid][s2] *= inv;
        }
        __syncthreads();
        {
            const int t0 = tid >> 4, d = tid & 15;
            for (int t = t0; t < 41; t += 16) {
                float a = 0.f;
                for (int s2 = 0; s2 < 41; ++s2) a = fmaf(ssc[t][s2], sxv[s2][d], a);
                g_buf[OFF_VAL + ((long)p * 41 + t) * 256 + head * 16 + d] = a;
            }
        }
        __syncthreads();
    }
}

// -------- word attention per pair: k=tanh(VAL@Wk+bk); w=softmax(k.qw*SCALE); REP=w^T VAL
__global__ __launch_bounds__(256) void k_wa(const float* __restrict__ Wk,
                                            const float* __restrict__ bk,
                                            const float* __restrict__ qw)
{
    const int p = blockIdx.x, tid = threadIdx.x;
    __shared__ __align__(16) float sval[41 * 256];
    __shared__ float skq[41];
    for (int i = tid; i < 41 * 256; i += 256) sval[i] = g_buf[OFF_VAL + (long)p * 41 * 256 + i];
    __syncthreads();
    const int tx = tid & 63, ty = tid >> 6;
    float acc[11][4] = {};
    for (int dd = 0; dd < 256; ++dd) {
        const float* wr = Wk + (long)dd * 200;
        float w0 = (tx < 200)       ? wr[tx]        : 0.f;
        float w1 = (tx + 64 < 200)  ? wr[tx + 64]   : 0.f;
        float w2 = (tx + 128 < 200) ? wr[tx + 128]  : 0.f;
        float w3 = (tx + 192 < 200) ? wr[tx + 192]  : 0.f;
        #pragma unroll
        for (int k = 0; k < 11; ++k) {
            int t = ty + 4 * k;
            if (t < 41) {
                float a = sval[t * 256 + dd];
                acc[k][0] = fmaf(a, w0, acc[k][0]);
                acc[k][1] = fmaf(a, w1, acc[k][1]);
                acc[k][2] = fmaf(a, w2, acc[k][2]);
                acc[k][3] = fmaf(a, w3, acc[k][3]);
            }
        }
    }
    #pragma unroll
    for (int k = 0; k < 11; ++k) {
        int t = ty + 4 * k;
        float s = 0.f;
        if (t < 41) {
            if (tx < 200)       s += tanhf(acc[k][0] + bk[tx])       * qw[tx];
            if (tx + 64 < 200)  s += tanhf(acc[k][1] + bk[tx + 64])  * qw[tx + 64];
            if (tx + 128 < 200) s += tanhf(acc[k][2] + bk[tx + 128]) * qw[tx + 128];
            if (tx + 192 < 200) s += tanhf(acc[k][3] + bk[tx + 192]) * qw[tx + 192];
        }
        #pragma unroll
        for (int off = 32; off > 0; off >>= 1) s += __shfl_down(s, off, 64);
        if (tx == 0 && t < 41) skq[t] = s;
    }
    __syncthreads();
    if (tid < 64) {
        float v = (tid < 41) ? skq[tid] * SCALE_C : -1e30f;
        float m = v;
        #pragma unroll
        for (int off = 32; off > 0; off >>= 1) m = fmaxf(m, __shfl_xor(m, off, 64));
        float e = (tid < 41) ? __expf(v - m) : 0.f;
        float sum = e;
        #pragma unroll
        for (int off = 32; off > 0; off >>= 1) sum += __shfl_xor(sum, off, 64);
        if (tid < 41) skq[tid] = e / sum;
    }
    __syncthreads();
    {
        float r = 0.f;
        for (int t = 0; t < 41; ++t) r = fmaf(skq[t], sval[t * 256 + tid], r);
        g_buf[OFF_REP + (long)p * 256 + tid] = r;
    }
}

// -------- final: mean over HIS, .Wl + bl, log_softmax over CDD --------
__global__ __launch_bounds__(256) void k_final(const float* __restrict__ Wl,
                                               const float* __restrict__ bl,
                                               float* __restrict__ out)
{
    const int b = blockIdx.x, tid = threadIdx.x;
    __shared__ float ssum[4];
    __shared__ float sc5[5];
    float wl = Wl[tid];
    for (int c = 0; c < 5; ++c) {
        float fv = 0.f;
        const long base = OFF_REP + ((long)(b * 5 + c) * 50) * 256 + tid;
        for (int h = 0; h < 50; ++h) fv += g_buf[base + (long)h * 256];
        float v = fv * (1.0f / 50.0f) * wl;
        #pragma unroll
        for (int off = 32; off > 0; off >>= 1) v += __shfl_down(v, off, 64);
        if ((tid & 63) == 0) ssum[tid >> 6] = v;
        __syncthreads();
        if (tid == 0) sc5[c] = ssum[0] + ssum[1] + ssum[2] + ssum[3] + bl[0];
        __syncthreads();
    }
    if (tid == 0) {
        float m = -1e30f;
        for (int c = 0; c < 5; ++c) m = fmaxf(m, sc5[c]);
        float sum = 0.f;
        for (int c = 0; c < 5; ++c) sum += expf(sc5[c] - m);
        float lse = m + logf(sum);
        for (int c = 0; c < 5; ++c) out[b * 5 + c] = sc5[c] - lse;
    }
}

extern "C" void kernel_launch(void* const* d_in, const int* in_sizes, int n_in,
                              void* d_out, int out_size, void* d_ws, size_t ws_size,
                              hipStream_t stream)
{
    (void)in_sizes; (void)n_in; (void)d_ws; (void)ws_size; (void)out_size;
    const int*   cand  = (const int*)d_in[0];
    const int*   clk   = (const int*)d_in[1];
    const float* emb   = (const float*)d_in[2];
    const float* convw = (const float*)d_in[3];
    const float* convb = (const float*)d_in[4];
    const float* Wq    = (const float*)d_in[5];
    const float* bq    = (const float*)d_in[6];
    const float* Wv    = (const float*)d_in[7];
    const float* bv    = (const float*)d_in[8];
    const float* Wk    = (const float*)d_in[9];
    const float* bk    = (const float*)d_in[10];
    const float* qw    = (const float*)d_in[11];
    const float* Wl    = (const float*)d_in[12];
    const float* bl    = (const float*)d_in[13];
    float* out = (float*)d_out;

    k_wvr <<<256, 256, 0, stream>>>(Wv);
    k_conv<<<1280, 256, 0, stream>>>(cand, clk, emb, convw, convb);

    // projections (K=256 GEMMs)
    gemm_k256<false><<<dim3(25, 4, 16), 256, 0, stream>>>(
        OFF_XC, 0, 0,  Wq, 0, 65536, 0,  bq, 0, 1, 256, 0,  OFF_QC, 409600, 256, 1600, 256);
    gemm_k256<true ><<<dim3(25, 4, 16), 256, 0, stream>>>(
        OFF_XC, 0, 0,  Wq, 0, 65536, 0,  nullptr, 0, 0, 0, 0,  OFF_QC2, 409600, 256, 1600, 256);
    gemm_k256<false><<<dim3(63, 4, 16), 256, 0, stream>>>(
        OFF_XM, 0, 0,  Wq, 0, 65536, 0,  bq, 0, 1, 256, 0,  OFF_QM, 1024000, 256, 4000, 256);
    gemm_k256<false><<<dim3(25, 4, 1), 256, 0, stream>>>(
        OFF_XC, 0, 0,  nullptr, OFF_WVR, 0, 0,  bv, 0, 1, 0, 0,  OFF_XVC, 0, 256, 1600, 256);
    gemm_k256<false><<<dim3(250, 4, 1), 256, 0, stream>>>(
        OFF_XH, 0, 0,  nullptr, OFF_WVR, 0, 0,  bv, 0, 1, 0, 0,  OFF_XVH, 0, 256, 16000, 256);
    gemm_k256<false><<<dim3(63, 4, 1), 256, 0, stream>>>(
        OFF_XM, 0, 0,  nullptr, OFF_WVR, 0, 0,  bv, 0, 1, 0, 0,  OFF_XVM, 0, 256, 4000, 256);
    k_bq<<<100, 256, 0, stream>>>(bq);

    // score blocks (NT GEMMs)
    gemm_k256<true><<<dim3(2, 2, 256), 256, 0, stream>>>(
        OFF_QC, 409600, 25600,  nullptr, OFF_XC, 0, 25600,  nullptr, 0, 0, 0, 0,
        OFF_SCC, 10000, 100, 100, 100);
    gemm_k256<true><<<dim3(2, 16, 256), 256, 0, stream>>>(
        OFF_QC, 409600, 25600,  nullptr, OFF_XH, 0, 256000,  nullptr, 0, 0, 0, 0,
        OFF_CR1, 100000, 1000, 100, 1000);
    gemm_k256<true><<<dim3(16, 2, 256), 256, 0, stream>>>(
        OFF_XH, 0, 256000,  nullptr, OFF_QC2, 409600, 25600,  nullptr, OFF_BQC, 2, 1600, 100,
        OFF_CR2, 100000, 100, 1000, 100);
    gemm_k256<true><<<dim3(1, 1, 1280), 256, 0, stream>>>(
        OFF_QM, 1024000, 12800,  nullptr, OFF_XC, 0, 5120,  nullptr, 0, 0, 0, 0,
        OFF_SRC, 1000, 20, 50, 20);
    gemm_k256<true><<<dim3(1, 1, 1280), 256, 0, stream>>>(
        OFF_QC, 409600, 5120,  nullptr, OFF_XM, 0, 12800,  nullptr, 0, 0, 0, 0,
        OFF_SCX, 1000, 50, 20, 50);
    k_shx<<<800, 256, 0, stream>>>(Wq, bq);

    k_attn <<<4000, 256, 0, stream>>>();
    k_wa   <<<4000, 256, 0, stream>>>(Wk, bk, qw);
    k_final<<<16, 256, 0, stream>>>(Wl, bl, out);
}